// Round 1
// baseline (314.719 us; speedup 1.0000x reference)
//
#include <hip/hip_runtime.h>
#include <hip/hip_bf16.h>

// ---------------------------------------------------------------------------
// QuixerCore: 10-qubit QSVT/LCU quantum circuit simulator.
// State layout per wave: n = r*64 + lane  (lane bits = n[0:5], reg bits = n[6:9])
// Qubit (wire) w lives at bit p = 9 - w of n.
//   wires 4..9 -> lane bits p=5..0 ; wires 0..3 -> register bits p=9..6
// ---------------------------------------------------------------------------

#define NQ   10
#define NT   32
#define DM   512
#define BATCH 128
#define NPQC 40
#define DIM  1024
#define NROWS (BATCH * NT)   // 4096

// ------------------------- gate primitives (per-wave) ----------------------

// RY(theta): out0 = c*a0 - s*a1 ; out1 = s*a0 + c*a1   (real 2x2 on complex amps)
template<int PT>
__device__ __forceinline__ void g_ry(float (&ar)[16], float (&ai)[16], int lane,
                                     float c, float s) {
  if constexpr (PT >= 6) {
    constexpr int m = 1 << (PT - 6);
#pragma unroll
    for (int r = 0; r < 16; ++r) {
      if (!(r & m)) {
        int r1 = r | m;
        float a0r = ar[r], a0i = ai[r], a1r = ar[r1], a1i = ai[r1];
        ar[r]  = c * a0r - s * a1r;  ai[r]  = c * a0i - s * a1i;
        ar[r1] = s * a0r + c * a1r;  ai[r1] = s * a0i + c * a1i;
      }
    }
  } else {
    constexpr int lm = 1 << PT;
    float se = (lane & lm) ? s : -s;   // bit0 lane: c*mine - s*partner ; bit1: c*mine + s*partner
#pragma unroll
    for (int r = 0; r < 16; ++r) {
      float pr = __shfl_xor(ar[r], lm);
      float pi = __shfl_xor(ai[r], lm);
      ar[r] = c * ar[r] + se * pr;
      ai[r] = c * ai[r] + se * pi;
    }
  }
}

// CRX(c_wire -> t_wire): where control bit == 1, apply RX:
//   out0 = c*a0 - i s*a1 ; out1 = -i s*a0 + c*a1  (symmetric in the pair)
//   re' = c*re + s*partner.im ; im' = c*im - s*partner.re
template<int PC, int PT>
__device__ __forceinline__ void g_crx(float (&ar)[16], float (&ai)[16], int lane,
                                      float c, float s) {
  if constexpr (PT >= 6) {
    constexpr int m = 1 << (PT - 6);
    bool lane_ok = (PC >= 6) || ((lane >> PC) & 1);
#pragma unroll
    for (int r = 0; r < 16; ++r) {
      if (!(r & m)) {
        if constexpr (PC >= 6) { if (!((r >> (PC - 6)) & 1)) continue; }
        int r1 = r | m;
        float a0r = ar[r], a0i = ai[r], a1r = ar[r1], a1i = ai[r1];
        float n0r = c * a0r + s * a1i, n0i = c * a0i - s * a1r;
        float n1r = c * a1r + s * a0i, n1i = c * a1i - s * a0r;
        if (lane_ok) { ar[r] = n0r; ai[r] = n0i; ar[r1] = n1r; ai[r1] = n1i; }
      }
    }
  } else {
    constexpr int lm = 1 << PT;
    bool lane_ok = (PC >= 6) || ((lane >> PC) & 1);
#pragma unroll
    for (int r = 0; r < 16; ++r) {
      bool act = lane_ok;
      if constexpr (PC >= 6) act = act && ((r >> (PC - 6)) & 1);
      float pr = __shfl_xor(ar[r], lm);   // shuffles must be unconditional
      float pi = __shfl_xor(ai[r], lm);
      float nr = c * ar[r] + s * pi;
      float ni = c * ai[r] - s * pr;
      if (act) { ar[r] = nr; ai[r] = ni; }
    }
  }
}

// ansatz14(q=10, layers=1), 40 gates.  PT = 9 - target_wire, PC = 9 - ctrl_wire.
__device__ __forceinline__ void apply_pqc(float (&ar)[16], float (&ai)[16],
                                          const float2* __restrict__ cs, int lane) {
  float2 t;
#define RYG(k, PT)     t = cs[k]; g_ry<PT>(ar, ai, lane, t.x, t.y);
#define CXG(k, PC, PT) t = cs[k]; g_crx<PC, PT>(ar, ai, lane, t.x, t.y);
  // ry wires 0..9
  RYG(0,9) RYG(1,8) RYG(2,7) RYG(3,6) RYG(4,5)
  RYG(5,4) RYG(6,3) RYG(7,2) RYG(8,1) RYG(9,0)
  // crx (c,t) = (9,0),(8,9),(7,8),(6,7),(5,6),(4,5),(3,4),(2,3),(1,2),(0,1)
  CXG(10,0,9) CXG(11,1,0) CXG(12,2,1) CXG(13,3,2) CXG(14,4,3)
  CXG(15,5,4) CXG(16,6,5) CXG(17,7,6) CXG(18,8,7) CXG(19,9,8)
  // ry wires 0..9
  RYG(20,9) RYG(21,8) RYG(22,7) RYG(23,6) RYG(24,5)
  RYG(25,4) RYG(26,3) RYG(27,2) RYG(28,1) RYG(29,0)
  // crx (c,t) = (9,8),(0,9),(1,0),(2,1),(3,2),(4,3),(5,4),(6,5),(7,6),(8,7)
  CXG(30,0,1) CXG(31,9,0) CXG(32,8,9) CXG(33,7,8) CXG(34,6,7)
  CXG(35,5,6) CXG(36,4,5) CXG(37,3,4) CXG(38,2,3) CXG(39,1,2)
#undef RYG
#undef CXG
}

// ------------------------- kernels -----------------------------------------

__global__ __launch_bounds__(256) void zero_kernel(float4* __restrict__ p, int n4) {
  int i = blockIdx.x * blockDim.x + threadIdx.x;
  if (i < n4) p[i] = make_float4(0.f, 0.f, 0.f, 0.f);
}

// Block per row (b,l): 40-dim output = emb_row . W^T + b; store (cos h, sin h), h = val/2.
// Block NROWS is special: ff_params cos/sin + normalized LCU weights.
__global__ __launch_bounds__(320) void params_kernel(
    const float* __restrict__ emb, const float* __restrict__ W,
    const float* __restrict__ bias,
    const float* __restrict__ lcu_re, const float* __restrict__ lcu_im,
    const float* __restrict__ ffp,
    float2* __restrict__ cs, float2* __restrict__ ffcs, float2* __restrict__ lcu) {
  int row = blockIdx.x;
  int t = threadIdx.x;
  if (row == NROWS) {
    if (t < NPQC) {
      float h = 0.5f * ffp[t];
      ffcs[t] = make_float2(cosf(h), sinf(h));
    }
    if (t == 64) {
      float ssum = 0.f;
      for (int i = 0; i < NT; ++i) {
        float re = lcu_re[i], im = lcu_im[i];
        ssum += sqrtf(re * re + im * im);
      }
      float inv = 1.f / ssum;
      for (int i = 0; i < NT; ++i)
        lcu[i] = make_float2(lcu_re[i] * inv, lcu_im[i] * inv);
    }
    return;
  }
  __shared__ float partials[NPQC][8];
  int k = t >> 3, part = t & 7;
  const float4* e4 = (const float4*)(emb + (size_t)row * DM + part * 64);
  const float4* w4 = (const float4*)(W + (size_t)k * DM + part * 64);
  float acc = 0.f;
#pragma unroll
  for (int i = 0; i < 16; ++i) {
    float4 a = e4[i], b = w4[i];
    acc += a.x * b.x + a.y * b.y + a.z * b.z + a.w * b.w;
  }
  partials[k][part] = acc;
  __syncthreads();
  if (t < NPQC) {
    float v = bias[t];
#pragma unroll
    for (int p = 0; p < 8; ++p) v += partials[t][p];
    float h = 0.5f * v;
    cs[(size_t)row * NPQC + t] = make_float2(cosf(h), sinf(h));
  }
}

// One wave per (b,l): state = U(params[b,l]) * src[b]  (src==nullptr -> e0),
// then atomicAdd lcu[l]*state into dst[b].
__global__ __launch_bounds__(256) void pqc_step(
    const float2* __restrict__ cs, const float2* __restrict__ lcu,
    const float2* __restrict__ src, float* __restrict__ dst) {
  int wid = (blockIdx.x * blockDim.x + threadIdx.x) >> 6;
  int lane = threadIdx.x & 63;
  int b = wid >> 5, l = wid & 31;
  const float2* csrow = cs + (size_t)wid * NPQC;

  float ar[16], ai[16];
  if (src) {
    const float2* s = src + (size_t)b * DIM;
#pragma unroll
    for (int r = 0; r < 16; ++r) {
      float2 v = s[r * 64 + lane];
      ar[r] = v.x; ai[r] = v.y;
    }
  } else {
#pragma unroll
    for (int r = 0; r < 16; ++r) { ar[r] = 0.f; ai[r] = 0.f; }
    if (lane == 0) ar[0] = 1.f;   // |0...0>
  }

  apply_pqc(ar, ai, csrow, lane);

  float2 w = lcu[l];
  float* d = dst + (size_t)b * DIM * 2;
#pragma unroll
  for (int r = 0; r < 16; ++r) {
    float cr = w.x * ar[r] - w.y * ai[r];
    float ci = w.x * ai[r] + w.y * ar[r];
    int n = r * 64 + lane;
    atomicAdd(d + 2 * n + 0, cr);
    atomicAdd(d + 2 * n + 1, ci);
  }
}

// One wave per batch element: acc = q0*e0 + q1*mono1 + q2*mono2 (global /sum|q| cancels
// under L2 normalization), normalize, apply ff PQC, measure X/Y/Z per wire.
__global__ __launch_bounds__(256) void final_kernel(
    const float2* __restrict__ mono1, const float2* __restrict__ mono2,
    const float* __restrict__ qsvt, const float2* __restrict__ ffcs,
    float* __restrict__ out) {
  int b = (blockIdx.x * blockDim.x + threadIdx.x) >> 6;
  int lane = threadIdx.x & 63;
  float q0 = qsvt[0], q1 = qsvt[1], q2 = qsvt[2];

  float ar[16], ai[16];
  const float2* m1 = mono1 + (size_t)b * DIM;
  const float2* m2 = mono2 + (size_t)b * DIM;
#pragma unroll
  for (int r = 0; r < 16; ++r) {
    int n = r * 64 + lane;
    float2 v1 = m1[n], v2 = m2[n];
    ar[r] = q1 * v1.x + q2 * v2.x;
    ai[r] = q1 * v1.y + q2 * v2.y;
  }
  if (lane == 0) ar[0] += q0;

  float nn = 0.f;
#pragma unroll
  for (int r = 0; r < 16; ++r) nn += ar[r] * ar[r] + ai[r] * ai[r];
#pragma unroll
  for (int o = 1; o < 64; o <<= 1) nn += __shfl_xor(nn, o);
  float inv = 1.f / sqrtf(nn);
#pragma unroll
  for (int r = 0; r < 16; ++r) { ar[r] *= inv; ai[r] *= inv; }

  apply_pqc(ar, ai, ffcs, lane);

  // measurement: wire w at bit p = 9-w. cross = sum conj(a0)*a1 over pairs across bit p.
#pragma unroll
  for (int w = 0; w < NQ; ++w) {
    const int p = 9 - w;
    float xr = 0.f, xi = 0.f, zz = 0.f;
    if (p >= 6) {
      const int m = 1 << (p - 6);
#pragma unroll
      for (int r = 0; r < 16; ++r) {
        float mag = ar[r] * ar[r] + ai[r] * ai[r];
        zz += (r & m) ? -mag : mag;
        if (!(r & m)) {
          int r1 = r | m;
          xr += ar[r] * ar[r1] + ai[r] * ai[r1];   // Re conj(a0)*a1
          xi += ar[r] * ai[r1] - ai[r] * ar[r1];   // Im conj(a0)*a1
        }
      }
    } else {
      const int lm = 1 << p;
      bool lo = !(lane & lm);
#pragma unroll
      for (int r = 0; r < 16; ++r) {
        float mag = ar[r] * ar[r] + ai[r] * ai[r];
        zz += lo ? mag : -mag;
        float pr = __shfl_xor(ar[r], lm);
        float pi = __shfl_xor(ai[r], lm);
        if (lo) {
          xr += ar[r] * pr + ai[r] * pi;
          xi += ar[r] * pi - ai[r] * pr;
        }
      }
    }
#pragma unroll
    for (int o = 1; o < 64; o <<= 1) {
      xr += __shfl_xor(xr, o);
      xi += __shfl_xor(xi, o);
      zz += __shfl_xor(zz, o);
    }
    if (lane == 0) {
      out[b * 30 + w]      = 2.f * xr;
      out[b * 30 + 10 + w] = 2.f * xi;
      out[b * 30 + 20 + w] = zz;
    }
  }
}

// ------------------------- launch ------------------------------------------

extern "C" void kernel_launch(void* const* d_in, const int* in_sizes, int n_in,
                              void* d_out, int out_size, void* d_ws, size_t ws_size,
                              hipStream_t stream) {
  const float* emb    = (const float*)d_in[0];
  const float* W      = (const float*)d_in[1];
  const float* bias   = (const float*)d_in[2];
  const float* lcu_re = (const float*)d_in[3];
  const float* lcu_im = (const float*)d_in[4];
  const float* qsvt   = (const float*)d_in[5];
  const float* ffp    = (const float*)d_in[6];
  float* out = (float*)d_out;

  char* ws = (char*)d_ws;
  // layout: cs[4096][40] f2 | ffcs[40] f2 | lcu[32] f2 | mono1[128][1024] f2 | mono2
  float2* cs    = (float2*)ws;                               // 1,310,720 B
  float2* ffcs  = (float2*)(ws + 1310720);                   //       320 B
  float2* lcu   = (float2*)(ws + 1311040);                   //       256 B
  float2* mono1 = (float2*)(ws + 1311296);                   // 1,048,576 B (16B-aligned)
  float2* mono2 = (float2*)(ws + 1311296 + 1048576);         // 1,048,576 B

  // zero mono1+mono2 (2 MB contiguous) — ws is poisoned before every launch
  zero_kernel<<<(131072 + 255) / 256, 256, 0, stream>>>((float4*)mono1, 131072);
  params_kernel<<<NROWS + 1, 320, 0, stream>>>(emb, W, bias, lcu_re, lcu_im, ffp,
                                               cs, ffcs, lcu);
  pqc_step<<<NROWS / 4, 256, 0, stream>>>(cs, lcu, nullptr, (float*)mono1);
  pqc_step<<<NROWS / 4, 256, 0, stream>>>(cs, lcu, mono1, (float*)mono2);
  final_kernel<<<BATCH / 4, 256, 0, stream>>>(mono1, mono2, qsvt, ffcs, out);
}